// Round 1
// 1918.396 us; speedup vs baseline: 1.4340x; 1.4340x over previous
//
#include <hip/hip_runtime.h>

#define NCOLS 10000
#define TK 32
#define EQ_CAP 1024
#define SMP 8
#define ROWS 48      // 6*SMP
#define APAD 50      // padded row stride for A (bank-spread + 8B align)

// monotone f32-bits -> u32 ordering key (ascending key == ascending float)
__device__ __forceinline__ unsigned int fkey(unsigned int u) {
    return (u & 0x80000000u) ? ~u : (u | 0x80000000u);
}

// One block per row: exact top-32 (value desc, lowest-index tie-break),
// output = the 32 winning indices sorted ascending.
// Single HBM pass (row cached in LDS as keys); threshold found by
// atomic-free binary search over the 16-bit key prefix.
__global__ __launch_bounds__(256, 3) void topk_rows(
        const float* __restrict__ sim, int* __restrict__ out_map) {
    const int row = blockIdx.x;
    const int tid = threadIdx.x;

    __shared__ __align__(16) unsigned int keys[NCOLS];
    __shared__ int wsum[4];
    __shared__ unsigned int cnt_gt, cnt_eq;
    __shared__ int gt_list[TK];
    __shared__ unsigned int eq_key[EQ_CAP];
    __shared__ int eq_idx[EQ_CAP];
    __shared__ int final_idx[TK];

    const uint4* rowv = (const uint4*)(sim + (size_t)row * NCOLS);
    for (int c = tid; c < NCOLS / 4; c += 256) {
        uint4 v = rowv[c];
        uint4 k;
        k.x = fkey(v.x); k.y = fkey(v.y); k.z = fkey(v.z); k.w = fkey(v.w);
        ((uint4*)keys)[c] = k;
    }
    if (tid == 0) { cnt_gt = 0; cnt_eq = 0; }
    __syncthreads();

    // find smallest P16 with count(key>>16 > P16) < TK  (16 bisect + 1 final count)
    unsigned lo = 0, hi = 65535;
    int total = 0;
    for (int it = 0; it < 17; ++it) {
        const unsigned mid = (it < 16) ? ((lo + hi) >> 1) : lo;
        int cnt = 0;
        for (int c = tid; c < NCOLS / 4; c += 256) {
            uint4 k = ((const uint4*)keys)[c];
            cnt += (k.x >> 16) > mid;
            cnt += (k.y >> 16) > mid;
            cnt += (k.z >> 16) > mid;
            cnt += (k.w >> 16) > mid;
        }
        #pragma unroll
        for (int off = 32; off; off >>= 1) cnt += __shfl_down(cnt, off);
        if ((tid & 63) == 0) wsum[tid >> 6] = cnt;
        __syncthreads();
        total = wsum[0] + wsum[1] + wsum[2] + wsum[3];
        if (it < 16) { if (total < TK) hi = mid; else lo = mid + 1; }
        __syncthreads();
    }
    const unsigned P = lo;
    const unsigned ngt = (unsigned)total;   // strictly-greater prefixes, < TK
    const unsigned m = TK - ngt;            // take m from the == bucket

    // collect winners and boundary-bucket candidates (from LDS)
    for (int c = tid; c < NCOLS / 4; c += 256) {
        uint4 k = ((const uint4*)keys)[c];
        unsigned ks[4] = { k.x, k.y, k.z, k.w };
        #pragma unroll
        for (int i = 0; i < 4; ++i) {
            const unsigned h16 = ks[i] >> 16;
            const int idx = c * 4 + i;
            if (h16 > P) {
                unsigned p = atomicAdd(&cnt_gt, 1u);
                gt_list[p] = idx;
            } else if (h16 == P) {
                unsigned p = atomicAdd(&cnt_eq, 1u);
                if (p < EQ_CAP) { eq_key[p] = ks[i]; eq_idx[p] = idx; }
            }
        }
    }
    __syncthreads();
    if (tid < (int)ngt) final_idx[tid] = gt_list[tid];
    const int E = (int)min(cnt_eq, (unsigned)EQ_CAP);
    // exact select of m best among boundary bucket: (full key desc, index asc)
    for (int i = tid; i < E; i += 256) {
        unsigned ki = eq_key[i]; int vi = eq_idx[i];
        int r = 0;
        for (int j = 0; j < E; ++j) {
            unsigned kj = eq_key[j];
            r += (kj > ki) || (kj == ki && eq_idx[j] < vi);
        }
        if (r < (int)m) final_idx[ngt + r] = vi;
    }
    __syncthreads();
    if (tid < TK) {
        int v = final_idx[tid];
        int r = 0;
        #pragma unroll
        for (int j = 0; j < TK; ++j) r += (final_idx[j] < v);
        out_map[(size_t)row * TK + r] = v;   // sorted ascending
    }
}

// W_t[k][j] = wf[j][k], W_t[k][128+j] = wi[j][k]   (k-major for coalesced staging)
__global__ void prep_wt(const float* __restrict__ wf, const float* __restrict__ wi,
                        float* __restrict__ W_t) {
    const int t = blockIdx.x * 256 + threadIdx.x;   // 16384 threads
    const int j = t >> 7, k = t & 127;
    W_t[k * 256 + j]       = wf[j * 128 + k];
    W_t[k * 256 + 128 + j] = wi[j * 128 + k];
}

// One block per sample: gather 64 neighbor rows, compute the two 32x7 convs,
// write c,d to cd[s][2][128]. Register-blocked, aligned float4 LDS reads.
__global__ __launch_bounds__(256, 3) void conv_cd(
        const int* __restrict__ data,
        const float* __restrict__ user_emb, const float* __restrict__ service_emb,
        const int* __restrict__ u_map, const int* __restrict__ s_map,
        const float* __restrict__ cnn_w, const float* __restrict__ cnn_b,
        const float* __restrict__ scnn_w, const float* __restrict__ scnn_b,
        float* __restrict__ cd) {
    const int s = blockIdx.x;
    const int tid = threadIdx.x;

    __shared__ float nb[2][32][136];   // logical h at [k][4+h]; zero pads at [0..3],[132..135]
    __shared__ float wbuf[2][224];
    __shared__ int nmr[2][32];
    __shared__ float part[2][4][128];

    const int uid = data[s * 3 + 1];
    const int sid = data[s * 3 + 2];

    if (tid < 32) {
        nmr[0][tid] = u_map[(size_t)uid * 32 + tid];
        nmr[1][tid] = s_map[(size_t)sid * 32 + tid];
    }
    if (tid < 224) { wbuf[0][tid] = cnn_w[tid]; wbuf[1][tid] = scnn_w[tid]; }
    __syncthreads();

    // gather 64 rows (float4) + zero the pads
    for (int e = tid; e < 2048; e += 256) {
        const int tb = e >> 10, k = (e >> 5) & 31, c = e & 31;
        const float* emb = tb ? service_emb : user_emb;
        float4 v = ((const float4*)(emb + (size_t)nmr[tb][k] * 128))[c];
        *((float4*)&nb[tb][k][4 + c * 4]) = v;
    }
    for (int e = tid; e < 512; e += 256) {
        const int tb = e >> 8, k = (e >> 3) & 31, i = e & 7;
        nb[tb][k][(i < 4) ? i : (128 + i)] = 0.f;
    }
    __syncthreads();

    // conv: thread = (tb = tid>>7, kg = 8-k group, hg -> 4 consecutive h)
    {
        const int tb = tid >> 7, r = tid & 127, kg = r >> 5, hg = r & 31, h0 = hg * 4;
        float a0 = 0.f, a1 = 0.f, a2 = 0.f, a3 = 0.f;
        for (int kk = 0; kk < 8; ++kk) {
            const int k = kg * 8 + kk;
            // padded[h0 .. h0+11] = logical[h0-4 .. h0+7], all 16B-aligned
            float4 x0 = *(const float4*)&nb[tb][k][h0];
            float4 x1 = *(const float4*)&nb[tb][k][h0 + 4];
            float4 x2 = *(const float4*)&nb[tb][k][h0 + 8];
            const float xa[12] = { x0.x, x0.y, x0.z, x0.w, x1.x, x1.y, x1.z, x1.w,
                                   x2.x, x2.y, x2.z, x2.w };
            const float* w = &wbuf[tb][k * 7];
            #pragma unroll
            for (int t = 0; t < 7; ++t) {
                const float wt = w[t];
                a0 += xa[1 + t] * wt;
                a1 += xa[2 + t] * wt;
                a2 += xa[3 + t] * wt;
                a3 += xa[4 + t] * wt;
            }
        }
        *(float4*)&part[tb][kg][h0] = make_float4(a0, a1, a2, a3);
    }
    __syncthreads();
    {
        const int tb = tid >> 7, h = tid & 127;
        float v = part[tb][0][h] + part[tb][1][h] + part[tb][2][h] + part[tb][3][h]
                + (tb ? scnn_b[0] : cnn_b[0]);
        cd[((size_t)s * 2 + tb) * 128 + h] = v;
    }
}

__device__ __forceinline__ float4 feat_ld(int f, int mm, int k4,
        const float* __restrict__ ue, const float* __restrict__ se,
        const float* __restrict__ cd,
        const int* uids, const int* sids, const int* sgl) {
    const float* base;
    if (f == 0)      base = ue + (size_t)uids[mm] * 128;
    else if (f == 1) base = se + (size_t)sids[mm] * 128;
    else             base = cd + ((size_t)sgl[mm] * 2 + (f - 2)) * 128;
    return ((const float4*)base)[k4];
}

// 8 samples per block: 48x256x128 GEMM (wf|wi stacked), gate+relu, norms,
// top-4 select, and fc -- all in LDS; tempt never hits HBM.
__global__ __launch_bounds__(256, 2) void fused_fc(
        const int* __restrict__ data,
        const float* __restrict__ user_emb, const float* __restrict__ service_emb,
        const float* __restrict__ cd, const float* __restrict__ W_t,
        const float* __restrict__ bi, const float* __restrict__ bfb,
        const float* __restrict__ fc_w, const float* __restrict__ fc_b,
        float* __restrict__ out, const int Btot) {
    const int s0 = blockIdx.x * SMP;
    const int tid = threadIdx.x;

    __shared__ float A[128 * APAD];     // s_pair transposed: A[k*APAD + row]
    __shared__ float WB[32 * 256];      // K-chunk of W_t; reused as tempt[48][128] in epilogue
    __shared__ float ps[ROWS][17];
    __shared__ float ss[ROWS];
    __shared__ int order[SMP][4];
    __shared__ int uids[SMP], sids[SMP], sgl[SMP];

    if (tid < SMP) {
        int s = s0 + tid; if (s >= Btot) s = Btot - 1;
        sgl[tid] = s;
        uids[tid] = data[s * 3 + 1];
        sids[tid] = data[s * 3 + 2];
    }
    __syncthreads();

    // stage A: pair rows (a+b, a+c, a+d, b+c, b+d, c+d), transposed [k][row]
    for (int e = tid; e < ROWS * 32; e += 256) {
        const int rw = e >> 5, k4 = e & 31;
        const int mm = rw / 6, p = rw - mm * 6;
        const int pi = (0x211000u >> (4 * p)) & 15;   // ii = 0,0,0,1,1,2
        const int pj = (0x332321u >> (4 * p)) & 15;   // jj = 1,2,3,2,3,3
        float4 va = feat_ld(pi, mm, k4, user_emb, service_emb, cd, uids, sids, sgl);
        float4 vb = feat_ld(pj, mm, k4, user_emb, service_emb, cd, uids, sids, sgl);
        const int kb = k4 * 4;
        A[(kb + 0) * APAD + rw] = va.x + vb.x;
        A[(kb + 1) * APAD + rw] = va.y + vb.y;
        A[(kb + 2) * APAD + rw] = va.z + vb.z;
        A[(kb + 3) * APAD + rw] = va.w + vb.w;
    }

    // GEMM: thread (ty 0..7 -> 6 rows, tx 0..31 -> 8 cols); cols 0..127 = wf, 128..255 = wi
    const int ty = tid >> 5, tx = tid & 31;
    float acc[6][8];
    #pragma unroll
    for (int r = 0; r < 6; ++r)
        #pragma unroll
        for (int c = 0; c < 8; ++c) acc[r][c] = 0.f;

    for (int kc = 0; kc < 4; ++kc) {
        __syncthreads();   // covers A staging (kc=0) / previous chunk reads (kc>0)
        for (int e = tid; e < 2048; e += 256) {
            const int kk = e >> 6, c4 = e & 63;
            ((float4*)&WB[kk * 256])[c4] =
                ((const float4*)(W_t + (size_t)(kc * 32 + kk) * 256))[c4];
        }
        __syncthreads();
        #pragma unroll 4
        for (int kk = 0; kk < 32; ++kk) {
            const int kb = kc * 32 + kk;
            const float2* ap = (const float2*)&A[kb * APAD + 6 * ty];
            float2 a01 = ap[0], a23 = ap[1], a45 = ap[2];
            const float4* wp = (const float4*)&WB[kk * 256 + 8 * tx];
            float4 w0 = wp[0], w1 = wp[1];
            const float av[6] = { a01.x, a01.y, a23.x, a23.y, a45.x, a45.y };
            #pragma unroll
            for (int r = 0; r < 6; ++r) {
                acc[r][0] += av[r] * w0.x; acc[r][1] += av[r] * w0.y;
                acc[r][2] += av[r] * w0.z; acc[r][3] += av[r] * w0.w;
                acc[r][4] += av[r] * w1.x; acc[r][5] += av[r] * w1.y;
                acc[r][6] += av[r] * w1.z; acc[r][7] += av[r] * w1.w;
            }
        }
    }
    __syncthreads();

    // epilogue: wf-half publishes F; wi-half computes gate+relu in place (-> tempt)
    float* Fbuf = WB;   // reused as [48][128]
    if (tx < 16) {
        #pragma unroll
        for (int r = 0; r < 6; ++r) {
            const int row = 6 * ty + r;
            *(float4*)&Fbuf[row * 128 + tx * 8] =
                make_float4(acc[r][0], acc[r][1], acc[r][2], acc[r][3]);
            *(float4*)&Fbuf[row * 128 + tx * 8 + 4] =
                make_float4(acc[r][4], acc[r][5], acc[r][6], acc[r][7]);
        }
    }
    __syncthreads();
    if (tx >= 16) {
        const int j0 = (tx - 16) * 8;
        float bfv[8], biv[8];
        *(float4*)&bfv[0] = *(const float4*)&bfb[j0];
        *(float4*)&bfv[4] = *(const float4*)&bfb[j0 + 4];
        *(float4*)&biv[0] = *(const float4*)&bi[j0];
        *(float4*)&biv[4] = *(const float4*)&bi[j0 + 4];
        #pragma unroll
        for (int r = 0; r < 6; ++r) {
            const int row = 6 * ty + r;
            float rss = 0.f;
            #pragma unroll
            for (int c = 0; c < 8; ++c) {
                const int j = j0 + c;
                const float F = Fbuf[row * 128 + j] + bfv[c];
                const float T = acc[r][c] + biv[c];
                const float sp = A[j * APAD + row];
                const float f = 1.0f / (1.0f + expf(-F));
                float v = f * T + (1.0f - f) * sp;
                v = v > 0.f ? v : 0.f;
                Fbuf[row * 128 + j] = v;   // in-place: same (row,j) this thread read
                rss += v * v;
            }
            ps[row][tx - 16] = rss;
        }
    }
    __syncthreads();
    if (tid < ROWS) {
        float t = 0.f;
        #pragma unroll
        for (int i = 0; i < 16; ++i) t += ps[tid][i];
        ss[tid] = t;
    }
    __syncthreads();
    if (tid < SMP) {
        const float* s6 = &ss[tid * 6];
        unsigned used = 0;
        #pragma unroll
        for (int r = 0; r < 4; ++r) {
            int best = -1; float bv = 0.f;
            for (int p = 0; p < 6; ++p) {
                if (used & (1u << p)) continue;
                if (best < 0 || s6[p] > bv) { best = p; bv = s6[p]; }
            }
            used |= 1u << best;
            order[tid][r] = best;   // descending norm, lowest index on ties
        }
    }
    __syncthreads();

    // fc: thread (m = tid>>5, oo = tid&31) computes outputs oo and oo+32 of sample m
    {
        const int m = tid >> 5, oo = tid & 31;
        float acc0 = fc_b[oo], acc1 = fc_b[oo + 32];
        #pragma unroll
        for (int g = 0; g < 4; ++g) {
            const int row = m * 6 + order[m][g];
            const float4* xr = (const float4*)&Fbuf[row * 128];
            const float4* wA = (const float4*)(fc_w + (size_t)oo * 512 + g * 128);
            const float4* wB = (const float4*)(fc_w + (size_t)(oo + 32) * 512 + g * 128);
            for (int c = 0; c < 32; ++c) {
                float4 x = xr[c], a = wA[c], b = wB[c];
                acc0 += x.x * a.x + x.y * a.y + x.z * a.z + x.w * a.w;
                acc1 += x.x * b.x + x.y * b.y + x.z * b.z + x.w * b.w;
            }
        }
        const int s = s0 + m;
        if (s < Btot) {
            out[(size_t)s * 64 + oo] = acc0;
            out[(size_t)s * 64 + oo + 32] = acc1;
        }
    }
}

extern "C" void kernel_launch(void* const* d_in, const int* in_sizes, int n_in,
                              void* d_out, int out_size, void* d_ws, size_t ws_size,
                              hipStream_t stream) {
    const int*   data        = (const int*)d_in[0];
    const float* user_sim    = (const float*)d_in[1];
    const float* service_sim = (const float*)d_in[2];
    const float* user_emb    = (const float*)d_in[3];
    const float* service_emb = (const float*)d_in[4];
    const float* cnn_w       = (const float*)d_in[5];
    const float* cnn_b       = (const float*)d_in[6];
    const float* scnn_w      = (const float*)d_in[7];
    const float* scnn_b      = (const float*)d_in[8];
    const float* wi          = (const float*)d_in[9];
    const float* bi          = (const float*)d_in[10];
    const float* wf          = (const float*)d_in[11];
    const float* bfb         = (const float*)d_in[12];
    const float* fc_w        = (const float*)d_in[13];
    const float* fc_b        = (const float*)d_in[14];

    const int U_n = in_sizes[3] / 128;   // 10000
    const int S_n = in_sizes[4] / 128;   // 10000
    const int B   = in_sizes[0] / 3;     // 16384

    // workspace layout (all 16B-aligned): u_map | s_map | W_t | cd   (~19.5 MB)
    int*   u_map_d = (int*)d_ws;
    int*   s_map_d = u_map_d + (size_t)U_n * 32;
    float* W_t     = (float*)(s_map_d + (size_t)S_n * 32);
    float* cd      = W_t + 128 * 256;

    topk_rows<<<U_n, 256, 0, stream>>>(user_sim, u_map_d);
    topk_rows<<<S_n, 256, 0, stream>>>(service_sim, s_map_d);
    prep_wt<<<64, 256, 0, stream>>>(wf, wi, W_t);
    conv_cd<<<B, 256, 0, stream>>>(data, user_emb, service_emb, u_map_d, s_map_d,
                                   cnn_w, cnn_b, scnn_w, scnn_b, cd);
    fused_fc<<<(B + SMP - 1) / SMP, 256, 0, stream>>>(
        data, user_emb, service_emb, cd, W_t, bi, bfb, fc_w, fc_b,
        (float*)d_out, B);
}